// Round 5
// baseline (233.198 us; speedup 1.0000x reference)
//
#include <hip/hip_runtime.h>
#include <math.h>

// Problem constants (fixed by the reference).
#define Bsz 64
#define Ssz 14
#define Isz 32
#define Csz 10
#define Dsz 16
#define Nsz (Ssz*Ssz*Isz)   // 6272
#define EPSF 1e-9f

#define CH  640             // n's per chunk == block size; CH%32==0 -> i = lane&31 invariant
#define NCH 10              // ceil(6272/640); chunk 9 has 512 valid n

// ---------------------------------------------------------------------------
// Load pose[n] (16 floats) via 4x float4.
// ---------------------------------------------------------------------------
__device__ __forceinline__ void load_pose(const float* __restrict__ poseb, int n, float* p)
{
    const float4* pp = reinterpret_cast<const float4*>(poseb + (size_t)n * Dsz);
    float4 a0 = pp[0], a1 = pp[1], a2 = pp[2], a3 = pp[3];
    p[0]=a0.x; p[1]=a0.y; p[2]=a0.z; p[3]=a0.w;
    p[4]=a1.x; p[5]=a1.y; p[6]=a1.z; p[7]=a1.w;
    p[8]=a2.x; p[9]=a2.y; p[10]=a2.z; p[11]=a2.w;
    p[12]=a3.x; p[13]=a3.y; p[14]=a3.z; p[15]=a3.w;
}

// vote = pose(4x4) @ Wr(4x4, REGISTERS) + coords on elems 0,1. Pure VALU.
__device__ __forceinline__ void vote_reg(const float* p, const float* Wr,
                                         float chh, float cww, float* v)
{
#pragma unroll
    for (int pr = 0; pr < 4; ++pr)
#pragma unroll
        for (int r = 0; r < 4; ++r)
            v[pr*4+r] = p[pr*4+0]*Wr[0*4+r] + p[pr*4+1]*Wr[1*4+r]
                      + p[pr*4+2]*Wr[2*4+r] + p[pr*4+3]*Wr[3*4+r];
    v[0] += chh;
    v[1] += cww;
}

// Each lane's loop-invariant W row: i = lane&31, class c. 16 VGPRs.
__device__ __forceinline__ void load_W_regs(const float* __restrict__ w,
                                            int lane, int c, float* Wr)
{
    const float4* ws = reinterpret_cast<const float4*>(w + (((lane & 31)*Csz + c) * Dsz));
    float4 b0 = ws[0], b1 = ws[1], b2 = ws[2], b3 = ws[3];
    Wr[0]=b0.x; Wr[1]=b0.y; Wr[2]=b0.z; Wr[3]=b0.w;
    Wr[4]=b1.x; Wr[5]=b1.y; Wr[6]=b1.z; Wr[7]=b1.w;
    Wr[8]=b2.x; Wr[9]=b2.y; Wr[10]=b2.z; Wr[11]=b2.w;
    Wr[12]=b3.x; Wr[13]=b3.y; Wr[14]=b3.z; Wr[15]=b3.w;
}

// ---------------------------------------------------------------------------
// M0: uniform-rr M-step partials. Block=(b,chunk), 640 thr = 10 waves,
// wave c accumulates S0,S1[16],S2[16] with w_n = act[n]/C. W in registers ->
// ZERO LDS in the loop. One butterfly -> partials[bc][chunk][33].
// ---------------------------------------------------------------------------
__global__ __launch_bounds__(640) void m0_kernel(
    const float* __restrict__ pose,     // [B][N][16]
    const float* __restrict__ act,      // [B][N]
    const float* __restrict__ w,        // [I][C][16]
    float* __restrict__ partials)       // [B*C][NCH][33]
{
    const int b = blockIdx.x, chunk = blockIdx.y;
    const int tid = threadIdx.x, c = tid >> 6, lane = tid & 63;

    float Wr[16];
    load_W_regs(w, lane, c, Wr);

    float s0 = 0.f, s1[Dsz], s2[Dsz];
#pragma unroll
    for (int d = 0; d < Dsz; ++d) { s1[d] = 0.f; s2[d] = 0.f; }

    const float* poseb = pose + (size_t)b * Nsz * Dsz;
    const float* actb  = act  + (size_t)b * Nsz;
    const int base = chunk * CH;

    for (int nl = lane; nl < CH; nl += 64) {
        const int n = base + nl;
        if (n < Nsz) {
            float p[16];
            load_pose(poseb, n, p);
            int hw = n >> 5;
            int wc = hw % Ssz, hr = hw / Ssz;
            float wgt = actb[n] * (1.0f/Csz);
            float v[16];
            vote_reg(p, Wr, (hr+0.5f)*(1.0f/Ssz), (wc+0.5f)*(1.0f/Ssz), v);
            s0 += wgt;
#pragma unroll
            for (int d = 0; d < Dsz; ++d) {
                float wv = wgt * v[d];
                s1[d] += wv;
                s2[d] += wv * v[d];
            }
        }
    }

#pragma unroll
    for (int m = 32; m >= 1; m >>= 1) {
        s0 += __shfl_xor(s0, m);
#pragma unroll
        for (int d = 0; d < Dsz; ++d) {
            s1[d] += __shfl_xor(s1[d], m);
            s2[d] += __shfl_xor(s2[d], m);
        }
    }
    if (lane == 0) {
        float* pt = partials + ((size_t)(b*Csz + c)*NCH + chunk)*33;
        pt[0] = s0;
#pragma unroll
        for (int d = 0; d < Dsz; ++d) { pt[1+d] = s1[d]; pt[17+d] = s2[d]; }
    }
}

// ---------------------------------------------------------------------------
// Fused finalize(prev M) + E + M. Block=(b,chunk), 640 thr = 10 waves,
// wave = class. W lives in per-lane REGISTERS (i = lane&31 loop-invariant).
//  F: redundantly reduce prev partials for this b -> prm[10][33] in LDS.
//  E: wave c computes zz[n][c] for all chunk n (register W + register
//     mean/invd) -> LDS zz[CH][11] (stride 11 -> 2-way = free).
//  softmax: thread-per-n, in-place zz -> rr*act.
//  M: wave c accumulates S0/S1/S2 (register W, 1 LDS read per n);
//     one butterfly -> part_out.
// LDS instrs/block ~450 (was ~3400 with LDS-resident W).
// ---------------------------------------------------------------------------
__global__ __launch_bounds__(640) void em_kernel(
    const float* __restrict__ pose,     // [B][N][16]
    const float* __restrict__ act,      // [B][N]
    const float* __restrict__ w,        // [I][C][16]
    const float* __restrict__ beta_v,   // [C]
    const float* __restrict__ beta_a,   // [C]
    const float* __restrict__ part_in,  // [B*C][NCH][33]
    float* __restrict__ part_out,       // [B*C][NCH][33]
    float inv_temp_prev)
{
    const int b = blockIdx.x, chunk = blockIdx.y;
    const int tid = threadIdx.x, wv = tid >> 6, lane = tid & 63;

    __shared__ float zz[CH][11];        // 28160 B; zz then rr in place
    __shared__ float Sv[Csz][33];
    __shared__ float prm[Csz][33];      // mean16, invd16, K
    __shared__ float lg[Csz][16];

    float Wr[16];
    load_W_regs(w, lane, wv, Wr);

    // ---- phase F: reduce prev partials for this b -> prm ----
    if (tid < Csz*33) {
        int c = tid / 33, j = tid - c*33;
        const float* pp = part_in + ((size_t)(b*Csz + c)*NCH)*33 + j;
        float s = 0.f;
        for (int ch2 = 0; ch2 < NCH; ++ch2) s += pp[ch2*33];
        Sv[c][j] = s;
    }
    __syncthreads();
    if (tid < Csz*Dsz) {
        int c = tid >> 4, d = tid & 15;
        float S0 = Sv[c][0];
        float mn  = Sv[c][1+d] / S0;
        float var = fmaxf(Sv[c][17+d] / S0 - mn*mn, 0.f);
        prm[c][d]    = mn;
        prm[c][16+d] = 1.f / (2.f*var + EPSF);
        lg[c][d]     = __logf(sqrtf(var) + EPSF);
    }
    __syncthreads();
    if (tid < Csz) {
        int c = tid;
        float sumlog = 0.f;
#pragma unroll
        for (int d = 0; d < Dsz; ++d) sumlog += lg[c][d];
        float cost = Sv[c][0] * (16.f * beta_v[c] + sumlog);
        float oact = 1.f / (1.f + __expf(-inv_temp_prev * (beta_a[c] - cost)));
        prm[c][32] = __logf(oact + EPSF) - sumlog;    // K[c]
    }
    __syncthreads();

    const int base = chunk * CH;
    const float* poseb = pose + (size_t)b * Nsz * Dsz;

    // ---- E phase: wave wv computes zz[.][wv] over the chunk ----
    {
        float mn[Dsz], iv[Dsz];
#pragma unroll
        for (int d = 0; d < Dsz; ++d) { mn[d] = prm[wv][d]; iv[d] = prm[wv][16+d]; }
        float Kc = prm[wv][32];

        for (int nl = lane; nl < CH; nl += 64) {
            const int n = base + nl;
            if (n < Nsz) {
                float p[16];
                load_pose(poseb, n, p);
                int hw = n >> 5;
                int wc = hw % Ssz, hr = hw / Ssz;
                float v[16];
                vote_reg(p, Wr, (hr+0.5f)*(1.0f/Ssz), (wc+0.5f)*(1.0f/Ssz), v);
                float quad = 0.f;
#pragma unroll
                for (int d = 0; d < Dsz; ++d) {
                    float dv = v[d] - mn[d];
                    quad += dv * dv * iv[d];
                }
                zz[nl][wv] = Kc - quad;
            }
        }
    }
    __syncthreads();

    // ---- softmax over c: thread-per-n, in place ----
    {
        const int n = base + tid;
        if (n < Nsz) {
            float z[Csz];
#pragma unroll
            for (int c = 0; c < Csz; ++c) z[c] = zz[tid][c];
            float zmax = z[0];
#pragma unroll
            for (int c = 1; c < Csz; ++c) zmax = fmaxf(zmax, z[c]);
            float zsum = 0.f;
#pragma unroll
            for (int c = 0; c < Csz; ++c) { z[c] = __expf(z[c] - zmax); zsum += z[c]; }
            float sc = __fdividef(act[(size_t)b*Nsz + n], zsum);
#pragma unroll
            for (int c = 0; c < Csz; ++c) zz[tid][c] = z[c] * sc;
        }
    }
    __syncthreads();

    // ---- M phase: wave wv accumulates with register W ----
    float s0 = 0.f, s1[Dsz], s2[Dsz];
#pragma unroll
    for (int d = 0; d < Dsz; ++d) { s1[d] = 0.f; s2[d] = 0.f; }

    for (int nl = lane; nl < CH; nl += 64) {
        const int n = base + nl;
        if (n < Nsz) {
            float p[16];
            load_pose(poseb, n, p);
            int hw = n >> 5;
            int wc = hw % Ssz, hr = hw / Ssz;
            float wgt = zz[nl][wv];
            float v[16];
            vote_reg(p, Wr, (hr+0.5f)*(1.0f/Ssz), (wc+0.5f)*(1.0f/Ssz), v);
            s0 += wgt;
#pragma unroll
            for (int d = 0; d < Dsz; ++d) {
                float wvv = wgt * v[d];
                s1[d] += wvv;
                s2[d] += wvv * v[d];
            }
        }
    }

#pragma unroll
    for (int m = 32; m >= 1; m >>= 1) {
        s0 += __shfl_xor(s0, m);
#pragma unroll
        for (int d = 0; d < Dsz; ++d) {
            s1[d] += __shfl_xor(s1[d], m);
            s2[d] += __shfl_xor(s2[d], m);
        }
    }
    if (lane == 0) {
        float* pt = part_out + ((size_t)(b*Csz + wv)*NCH + chunk)*33;
        pt[0] = s0;
#pragma unroll
        for (int d = 0; d < Dsz; ++d) { pt[1+d] = s1[d]; pt[17+d] = s2[d]; }
    }
}

// ---------------------------------------------------------------------------
// Final finalize: thread per (b,c): reduce last partials, mean + o_act
// (inv_temp=3), write outputs.
// ---------------------------------------------------------------------------
__global__ __launch_bounds__(64) void fin_kernel(
    const float* __restrict__ partials, // [B*C][NCH][33]
    const float* __restrict__ beta_v,
    const float* __restrict__ beta_a,
    float* __restrict__ out,            // [B][C][16] then [B][C]
    float inv_temp)
{
    const int bc = blockIdx.x * 64 + threadIdx.x;
    if (bc >= Bsz*Csz) return;
    const int c = bc % Csz;

    float S[33];
#pragma unroll
    for (int j = 0; j < 33; ++j) S[j] = 0.f;
    const float* pb = partials + (size_t)bc * NCH * 33;
    for (int ch2 = 0; ch2 < NCH; ++ch2)
#pragma unroll
        for (int j = 0; j < 33; ++j) S[j] += pb[ch2*33 + j];

    float S0 = S[0], rS0 = 1.f / S0;
    float sumlog = 0.f;
    float* om = out + (size_t)bc * Dsz;
#pragma unroll
    for (int d = 0; d < Dsz; ++d) {
        float mn  = S[1+d] * rS0;
        float var = fmaxf(S[17+d] * rS0 - mn*mn, 0.f);
        sumlog += __logf(sqrtf(var) + EPSF);
        om[d] = mn;
    }
    float cost = S0 * (16.f * beta_v[c] + sumlog);
    float oact = 1.f / (1.f + __expf(-inv_temp * (beta_a[c] - cost)));
    out[Bsz*Csz*Dsz + bc] = oact;
}

// ---------------------------------------------------------------------------
// 4 dispatches: M0 -> EM1 -> EM2 -> FIN. Workspace: partials A,B = 1.69 MB.
// rr/zz live in LDS only; W lives in per-lane registers inside the loops.
// ---------------------------------------------------------------------------
extern "C" void kernel_launch(void* const* d_in, const int* in_sizes, int n_in,
                              void* d_out, int out_size, void* d_ws, size_t ws_size,
                              hipStream_t stream)
{
    const float* pose = (const float*)d_in[0];
    const float* act  = (const float*)d_in[1];
    const float* w    = (const float*)d_in[2];
    const float* bv   = (const float*)d_in[3];
    const float* ba   = (const float*)d_in[4];
    float* out = (float*)d_out;

    float* partA = (float*)d_ws;
    float* partB = partA + (size_t)Bsz*Csz*NCH*33;

    dim3 grid(Bsz, NCH);

    m0_kernel<<<grid, CH, 0, stream>>>(pose, act, w, partA);
    em_kernel<<<grid, CH, 0, stream>>>(pose, act, w, bv, ba, partA, partB, 1.0f);
    em_kernel<<<grid, CH, 0, stream>>>(pose, act, w, bv, ba, partB, partA, 2.0f);
    fin_kernel<<<(Bsz*Csz + 63)/64, 64, 0, stream>>>(partA, bv, ba, out, 3.0f);
}